// Round 4
// baseline (479.363 us; speedup 1.0000x reference)
//
#include <hip/hip_runtime.h>
#include <cstdint>

typedef unsigned long long u64;
typedef unsigned short u16;

#define HWSZ 3136      // 56*56
#define WD 56
#define NPIX 50176     // 16*3136

__device__ __forceinline__ float clampf(float v){ return fminf(1.0f, fmaxf(-1.0f, v)); }
__device__ __forceinline__ u16 f2bf(float f){
    unsigned u = __float_as_uint(f);
    return (u16)((u + 0x7fffu + ((u >> 16) & 1u)) >> 16);
}
__device__ __forceinline__ float bf2f(u16 h){ return __uint_as_float(((unsigned)h) << 16); }

// ---------------- weight prep: pack sign bits, fold bn ----------------
__global__ __launch_bounds__(256) void k_wprep(
    const float* __restrict__ w1, const float* __restrict__ w2,
    const float* __restrict__ g1, const float* __restrict__ be1,
    const float* __restrict__ m1, const float* __restrict__ v1,
    const float* __restrict__ g2, const float* __restrict__ be2,
    const float* __restrict__ m2, const float* __restrict__ v2,
    u64* __restrict__ w1b, u64* __restrict__ w2e, u64* __restrict__ w2o,
    float* __restrict__ A1, float* __restrict__ B1,
    float* __restrict__ A2, float* __restrict__ B2)
{
    int co  = blockIdx.x;
    int tid = threadIdx.x;
    int wv = tid >> 6, lane = tid & 63;
    int ci = (wv << 6) + lane;          // 0..255

    float s1 = 0.f, s2 = 0.f;
    const float* w1p = w1 + ((size_t)co * 256 + ci) * 9;
#pragma unroll
    for (int t = 0; t < 9; t++) {
        float v = w1p[t];
        s1 += fabsf(v);
        u64 bal = __ballot(v >= 0.f);
        if (lane == 0) w1b[(co * 9 + t) * 4 + wv] = bal;
    }
    const float* wep = w2 + ((size_t)co * 512 + 2 * ci) * 9;
    const float* wop = wep + 9;
#pragma unroll
    for (int t = 0; t < 9; t++) {
        float ve = wep[t], vo = wop[t];
        s2 += fabsf(ve) + fabsf(vo);
        u64 bale = __ballot(ve >= 0.f);
        u64 balo = __ballot(vo >= 0.f);
        if (lane == 0) { w2e[(co * 9 + t) * 4 + wv] = bale; w2o[(co * 9 + t) * 4 + wv] = balo; }
    }
    __shared__ float red1[256], red2[256];
    red1[tid] = s1; red2[tid] = s2;
    __syncthreads();
    for (int off = 128; off > 0; off >>= 1) {
        if (tid < off) { red1[tid] += red1[tid + off]; red2[tid] += red2[tid + off]; }
        __syncthreads();
    }
    if (tid == 0) {
        float scale1 = red1[0] / 2304.f;
        float scale2 = red2[0] / 4608.f;
        float inv1 = g1[co] / sqrtf(v1[co] + 1e-5f);
        float inv2 = g2[co] / sqrtf(v2[co] + 1e-5f);
        A1[co] = scale1 * inv1;  B1[co] = be1[co] - m1[co] * inv1;
        A2[co] = scale2 * inv2;  B2[co] = be2[co] - m2[co] * inv2;
    }
}

// ---------------- activation packing ----------------
__global__ __launch_bounds__(256) void k_pack(
    const float* __restrict__ x, const float* __restrict__ mb,
    u64* __restrict__ bitsA, u64* __restrict__ bitsI)
{
    int tid = threadIdx.x;
    int p = blockIdx.x * 256 + tid;          // pixel (b,hw)
    int q = blockIdx.y;                       // 64-channel quarter
    int b = p / HWSZ, hw = p % HWSZ;
    const float* xa = x + ((size_t)(b * 512 + q * 64)) * HWSZ + hw;
    const float* xi = x + ((size_t)(b * 512 + 256 + q * 64)) * HWSZ + hw;
    const float* mbq = mb + q * 64;
    u64 wa = 0, wi = 0;
#pragma unroll 8
    for (int j = 0; j < 64; j++) {
        float va = xa[(size_t)j * HWSZ];
        float vi = xi[(size_t)j * HWSZ] + mbq[j];
        wa |= (u64)(va >= 0.f) << j;
        wi |= (u64)(vi >= 0.f) << j;
    }
    bitsA[(size_t)p * 4 + q] = wa;
    bitsI[(size_t)p * 4 + q] = wi;
}

// ---------------- conv1: 256->256 binary conv + bn + residual + clip ----------------
// wave g owns co [q*64+g*16,+16); lane owns 4 adjacent pixels (56%4==0: same row)
__global__ __launch_bounds__(256, 3) void k_conv1(
    const float* __restrict__ x, const u64* __restrict__ bitsA,
    const u64* __restrict__ w1b, const float* __restrict__ A1, const float* __restrict__ B1,
    u64* __restrict__ bitsC, u16* __restrict__ c1v)
{
    __shared__ u64 sw[2304];         // 64 co * 9 taps * 4 words
    __shared__ float sA[64], sB[64];
    __shared__ u16 spart[4][256];
    int tid = threadIdx.x;
    int q = blockIdx.y;
    int cobase = q * 64;
    {
        const u64* src = w1b + (size_t)cobase * 36;
#pragma unroll
        for (int i = 0; i < 9; i++) sw[tid + i * 256] = src[tid + i * 256];
        if (tid < 64) { sA[tid] = A1[cobase + tid]; sB[tid] = B1[cobase + tid]; }
    }
    __syncthreads();

    int g = tid >> 6, lane = tid & 63;
    int pix0 = blockIdx.x * 256 + lane * 4;
    int b = pix0 / HWSZ, hw = pix0 % HWSZ;
    int h = hw / WD, w = hw % WD;     // w % 4 == 0

    int acc[16][4];
#pragma unroll
    for (int co = 0; co < 16; co++)
#pragma unroll
        for (int p = 0; p < 4; p++) acc[co][p] = 0;

#pragma unroll 1
    for (int dy = -1; dy <= 1; dy++) {
        bool rowok = ((unsigned)(h + dy)) < (unsigned)WD;
        u64 pos[6][4];
        int m[6];
#pragma unroll
        for (int k = 0; k < 6; k++) {
            int c = w - 1 + k;
            bool ok = rowok && ((unsigned)c < (unsigned)WD);
            int pg = pix0 + dy * WD + (k - 1);
            pg = pg < 0 ? 0 : (pg > NPIX - 1 ? NPIX - 1 : pg);
            const ulonglong2* pb = (const ulonglong2*)(bitsA + (size_t)pg * 4);
            ulonglong2 a01 = pb[0], a23 = pb[1];
            pos[k][0] = a01.x; pos[k][1] = a01.y; pos[k][2] = a23.x; pos[k][3] = a23.y;
            m[k] = ok ? -1 : 0;
        }
        int tbase = (dy + 1) * 3;
#pragma unroll
        for (int dx = 0; dx < 3; dx++) {
            int t = tbase + dx;
#pragma unroll
            for (int co = 0; co < 16; co++) {
                const u64* wp = &sw[(((g << 4) + co) * 9 + t) * 4];
                u64 w0 = wp[0], w1_ = wp[1], w2_ = wp[2], w3_ = wp[3];
#pragma unroll
                for (int p = 0; p < 4; p++) {
                    int k = dx + p;
                    int pt = __popcll(pos[k][0] ^ w0) + __popcll(pos[k][1] ^ w1_)
                           + __popcll(pos[k][2] ^ w2_) + __popcll(pos[k][3] ^ w3_);
                    acc[co][p] += pt & m[k];
                }
            }
        }
    }

    int rowsv = 3 - (h == 0) - (h == WD - 1);
    int nv[4];
#pragma unroll
    for (int p = 0; p < 4; p++) {
        int wp_ = w + p;
        nv[p] = rowsv * (3 - (wp_ == 0) - (wp_ == WD - 1));
    }

    unsigned sb[4] = {0, 0, 0, 0};
    bool wr = (q < 2);
#pragma unroll
    for (int co = 0; co < 16; co++) {
        int col = (g << 4) + co;
        int coG = cobase + col;
        float A = sA[col], B = sB[col];
        float4 xr = *(const float4*)(x + (size_t)(b * 512 + coG) * HWSZ + hw);
        float v0 = (float)((nv[0] << 8) - 2 * acc[co][0]) * A + B + xr.x;
        float v1 = (float)((nv[1] << 8) - 2 * acc[co][1]) * A + B + xr.y;
        float v2 = (float)((nv[2] << 8) - 2 * acc[co][2]) * A + B + xr.z;
        float v3 = (float)((nv[3] << 8) - 2 * acc[co][3]) * A + B + xr.w;
        sb[0] |= (unsigned)(v0 >= 0.f) << co;
        sb[1] |= (unsigned)(v1 >= 0.f) << co;
        sb[2] |= (unsigned)(v2 >= 0.f) << co;
        sb[3] |= (unsigned)(v3 >= 0.f) << co;
        if (wr) {
            ushort4 st;
            st.x = f2bf(clampf(v0)); st.y = f2bf(clampf(v1));
            st.z = f2bf(clampf(v2)); st.w = f2bf(clampf(v3));
            *(ushort4*)(c1v + (size_t)coG * NPIX + pix0) = st;
        }
    }
#pragma unroll
    for (int p = 0; p < 4; p++) spart[g][lane * 4 + p] = (u16)sb[p];
    __syncthreads();
    if (g == 0) {
#pragma unroll
        for (int p = 0; p < 4; p++) {
            int pi = lane * 4 + p;
            u64 word = (u64)spart[0][pi] | ((u64)spart[1][pi] << 16)
                     | ((u64)spart[2][pi] << 32) | ((u64)spart[3][pi] << 48);
            bitsC[(size_t)(pix0 + p) * 4 + q] = word;
        }
    }
}

// ---------------- conv2: 512->256 binary conv + bn + shuffled residual + clip ----------------
// two passes (bitsC x w2e, bitsI x w2o) share acc -> only 6x4 u64 positions live
__global__ __launch_bounds__(256, 3) void k_conv2(
    const float* __restrict__ x, const float* __restrict__ mb,
    const u64* __restrict__ bitsC, const u64* __restrict__ bitsI,
    const u64* __restrict__ w2e, const u64* __restrict__ w2o,
    const float* __restrict__ A2, const float* __restrict__ B2,
    const u16* __restrict__ c1v, float* __restrict__ out)
{
    __shared__ u64 se[2304], so[2304];
    __shared__ float sA[64], sB[64], sM[32];
    int tid = threadIdx.x;
    int q = blockIdx.y;
    int cobase = q * 64;
    {
        const u64* srcE = w2e + (size_t)cobase * 36;
        const u64* srcO = w2o + (size_t)cobase * 36;
#pragma unroll
        for (int i = 0; i < 9; i++) { se[tid + i * 256] = srcE[tid + i * 256]; so[tid + i * 256] = srcO[tid + i * 256]; }
        if (tid < 64) { sA[tid] = A2[cobase + tid]; sB[tid] = B2[cobase + tid]; }
        if (tid < 32) { sM[tid] = mb[q * 32 + tid]; }
    }
    __syncthreads();

    int g = tid >> 6, lane = tid & 63;
    int pix0 = blockIdx.x * 256 + lane * 4;
    int b = pix0 / HWSZ, hw = pix0 % HWSZ;
    int h = hw / WD, w = hw % WD;

    int acc[16][4];
#pragma unroll
    for (int co = 0; co < 16; co++)
#pragma unroll
        for (int p = 0; p < 4; p++) acc[co][p] = 0;

#pragma unroll 1
    for (int pass = 0; pass < 2; pass++) {
        const u64* bits = pass ? bitsI : bitsC;
        const u64* swp  = pass ? so : se;
#pragma unroll 1
        for (int dy = -1; dy <= 1; dy++) {
            bool rowok = ((unsigned)(h + dy)) < (unsigned)WD;
            u64 pos[6][4];
            int m[6];
#pragma unroll
            for (int k = 0; k < 6; k++) {
                int c = w - 1 + k;
                bool ok = rowok && ((unsigned)c < (unsigned)WD);
                int pg = pix0 + dy * WD + (k - 1);
                pg = pg < 0 ? 0 : (pg > NPIX - 1 ? NPIX - 1 : pg);
                const ulonglong2* pb = (const ulonglong2*)(bits + (size_t)pg * 4);
                ulonglong2 a01 = pb[0], a23 = pb[1];
                pos[k][0] = a01.x; pos[k][1] = a01.y; pos[k][2] = a23.x; pos[k][3] = a23.y;
                m[k] = ok ? -1 : 0;
            }
            int tbase = (dy + 1) * 3;
#pragma unroll
            for (int dx = 0; dx < 3; dx++) {
                int t = tbase + dx;
#pragma unroll
                for (int co = 0; co < 16; co++) {
                    const u64* wp = &swp[(((g << 4) + co) * 9 + t) * 4];
                    u64 w0 = wp[0], w1_ = wp[1], w2_ = wp[2], w3_ = wp[3];
#pragma unroll
                    for (int p = 0; p < 4; p++) {
                        int k = dx + p;
                        int pt = __popcll(pos[k][0] ^ w0) + __popcll(pos[k][1] ^ w1_)
                               + __popcll(pos[k][2] ^ w2_) + __popcll(pos[k][3] ^ w3_);
                        acc[co][p] += pt & m[k];
                    }
                }
            }
        }
    }

    int rowsv = 3 - (h == 0) - (h == WD - 1);
    int nv[4];
#pragma unroll
    for (int p = 0; p < 4; p++) {
        int wp_ = w + p;
        nv[p] = rowsv * (3 - (wp_ == 0) - (wp_ == WD - 1));
    }

#pragma unroll
    for (int co = 0; co < 16; co++) {
        int col = (g << 4) + co;
        int coG = cobase + col;
        int cg2 = coG >> 1;
        float A = sA[col], B = sB[col];
        float r0, r1, r2, r3;
        if ((co & 1) == 0) {
            ushort4 cv = *(const ushort4*)(c1v + (size_t)cg2 * NPIX + pix0);
            r0 = bf2f(cv.x); r1 = bf2f(cv.y); r2 = bf2f(cv.z); r3 = bf2f(cv.w);
        } else {
            float4 xi = *(const float4*)(x + (size_t)(b * 512 + 256 + cg2) * HWSZ + hw);
            float mbv = sM[col >> 1];
            r0 = xi.x + mbv; r1 = xi.y + mbv; r2 = xi.z + mbv; r3 = xi.w + mbv;
        }
        float4 ov;
        ov.x = clampf((float)((nv[0] << 9) - 2 * acc[co][0]) * A + B + r0);
        ov.y = clampf((float)((nv[1] << 9) - 2 * acc[co][1]) * A + B + r1);
        ov.z = clampf((float)((nv[2] << 9) - 2 * acc[co][2]) * A + B + r2);
        ov.w = clampf((float)((nv[3] << 9) - 2 * acc[co][3]) * A + B + r3);
        *(float4*)(out + (size_t)(b * 256 + coG) * HWSZ + hw) = ov;
    }
}

extern "C" void kernel_launch(void* const* d_in, const int* in_sizes, int n_in,
                              void* d_out, int out_size, void* d_ws, size_t ws_size,
                              hipStream_t stream)
{
    const float* x   = (const float*)d_in[0];
    const float* w1  = (const float*)d_in[1];
    const float* w2  = (const float*)d_in[2];
    const float* g1  = (const float*)d_in[3];
    const float* be1 = (const float*)d_in[4];
    const float* m1  = (const float*)d_in[5];
    const float* v1  = (const float*)d_in[6];
    const float* g2  = (const float*)d_in[7];
    const float* be2 = (const float*)d_in[8];
    const float* m2  = (const float*)d_in[9];
    const float* v2  = (const float*)d_in[10];
    const float* mb  = (const float*)d_in[11];

    char* ws = (char*)d_ws;
    u64* w1b = (u64*)ws; ws += 73728;
    u64* w2e = (u64*)ws; ws += 73728;
    u64* w2o = (u64*)ws; ws += 73728;
    float* A1 = (float*)ws; ws += 1024;
    float* B1 = (float*)ws; ws += 1024;
    float* A2 = (float*)ws; ws += 1024;
    float* B2 = (float*)ws; ws += 1024;
    u64* bitsA = (u64*)ws; ws += (size_t)NPIX * 4 * 8;
    u64* bitsI = (u64*)ws; ws += (size_t)NPIX * 4 * 8;
    u64* bitsC = (u64*)ws; ws += (size_t)NPIX * 4 * 8;
    u16* c1v = (u16*)ws; ws += (size_t)128 * NPIX * 2;

    hipLaunchKernelGGL(k_wprep, dim3(256), dim3(256), 0, stream,
                       w1, w2, g1, be1, m1, v1, g2, be2, m2, v2,
                       w1b, w2e, w2o, A1, B1, A2, B2);
    hipLaunchKernelGGL(k_pack, dim3(196, 4), dim3(256), 0, stream, x, mb, bitsA, bitsI);
    hipLaunchKernelGGL(k_conv1, dim3(196, 4), dim3(256), 0, stream,
                       x, bitsA, w1b, A1, B1, bitsC, c1v);
    hipLaunchKernelGGL(k_conv2, dim3(196, 4), dim3(256), 0, stream,
                       x, mb, bitsC, bitsI, w2e, w2o, A2, B2, c1v, (float*)d_out);
}

// Round 7
// 453.871 us; speedup vs baseline: 1.0562x; 1.0562x over previous
//
#include <hip/hip_runtime.h>
#include <cstdint>

typedef unsigned long long u64;
typedef unsigned short u16;

#define HWSZ 3136      // 56*56
#define WD 56
#define NPIX 50176     // 16*3136

__device__ __forceinline__ float clampf(float v){ return fminf(1.0f, fmaxf(-1.0f, v)); }
__device__ __forceinline__ u16 f2bf(float f){
    unsigned u = __float_as_uint(f);
    return (u16)((u + 0x7fffu + ((u >> 16) & 1u)) >> 16);
}
__device__ __forceinline__ float bf2f(u16 h){ return __uint_as_float(((unsigned)h) << 16); }

// load 6 neighbor positions (w-1 .. w+4) for row h+dy into plo/phi, masks into m
#define LOADPOS(BITS)                                                          \
    {                                                                          \
        bool rowok = ((unsigned)(h + dy)) < (unsigned)WD;                      \
        _Pragma("unroll")                                                      \
        for (int k = 0; k < 6; k++) {                                          \
            int c = w - 1 + k;                                                 \
            bool ok = rowok && ((unsigned)c < (unsigned)WD);                   \
            int pg = pix0 + dy * WD + (k - 1);                                 \
            pg = pg < 0 ? 0 : (pg > NPIX - 1 ? NPIX - 1 : pg);                 \
            const ulonglong2* pb = (const ulonglong2*)((BITS) + (size_t)pg * 4);\
            plo[k] = pb[0]; phi[k] = pb[1];                                    \
            m[k] = ok ? -1 : 0;                                                \
        }                                                                      \
    }

// accumulate 3 taps x 8 cos x 4 pixels from LDS weights SW with co offset COOFF
#define TAPROW(SW, ACC, COOFF)                                                 \
    {                                                                          \
        int tbase = (dy + 1) * 3;                                              \
        _Pragma("unroll")                                                      \
        for (int dx = 0; dx < 3; dx++) {                                       \
            int t = tbase + dx;                                                \
            _Pragma("unroll")                                                  \
            for (int co = 0; co < 8; co++) {                                   \
                const u64* wp = &(SW)[(((g << 4) + (COOFF) + co) * 9 + t) * 4];\
                ulonglong2 wA = *(const ulonglong2*)wp;                        \
                ulonglong2 wB = *(const ulonglong2*)(wp + 2);                  \
                _Pragma("unroll")                                              \
                for (int p = 0; p < 4; p++) {                                  \
                    int k = dx + p;                                            \
                    int pt = __popcll(plo[k].x ^ wA.x) + __popcll(plo[k].y ^ wA.y) \
                           + __popcll(phi[k].x ^ wB.x) + __popcll(phi[k].y ^ wB.y);\
                    ACC[co][p] += pt & m[k];                                   \
                }                                                              \
            }                                                                  \
        }                                                                      \
    }

// ---------------- weight prep: pack sign bits, fold bn ----------------
__global__ __launch_bounds__(256) void k_wprep(
    const float* __restrict__ w1, const float* __restrict__ w2,
    const float* __restrict__ g1, const float* __restrict__ be1,
    const float* __restrict__ m1, const float* __restrict__ v1,
    const float* __restrict__ g2, const float* __restrict__ be2,
    const float* __restrict__ m2, const float* __restrict__ v2,
    u64* __restrict__ w1b, u64* __restrict__ w2e, u64* __restrict__ w2o,
    float* __restrict__ A1, float* __restrict__ B1,
    float* __restrict__ A2, float* __restrict__ B2)
{
    int co  = blockIdx.x;
    int tid = threadIdx.x;
    int wv = tid >> 6, lane = tid & 63;
    int ci = (wv << 6) + lane;          // 0..255

    float s1 = 0.f, s2 = 0.f;
    const float* w1p = w1 + ((size_t)co * 256 + ci) * 9;
#pragma unroll
    for (int t = 0; t < 9; t++) {
        float v = w1p[t];
        s1 += fabsf(v);
        u64 bal = __ballot(v >= 0.f);
        if (lane == 0) w1b[(co * 9 + t) * 4 + wv] = bal;
    }
    const float* wep = w2 + ((size_t)co * 512 + 2 * ci) * 9;
    const float* wop = wep + 9;
#pragma unroll
    for (int t = 0; t < 9; t++) {
        float ve = wep[t], vo = wop[t];
        s2 += fabsf(ve) + fabsf(vo);
        u64 bale = __ballot(ve >= 0.f);
        u64 balo = __ballot(vo >= 0.f);
        if (lane == 0) { w2e[(co * 9 + t) * 4 + wv] = bale; w2o[(co * 9 + t) * 4 + wv] = balo; }
    }
    __shared__ float red1[256], red2[256];
    red1[tid] = s1; red2[tid] = s2;
    __syncthreads();
    for (int off = 128; off > 0; off >>= 1) {
        if (tid < off) { red1[tid] += red1[tid + off]; red2[tid] += red2[tid + off]; }
        __syncthreads();
    }
    if (tid == 0) {
        float scale1 = red1[0] / 2304.f;
        float scale2 = red2[0] / 4608.f;
        float inv1 = g1[co] / sqrtf(v1[co] + 1e-5f);
        float inv2 = g2[co] / sqrtf(v2[co] + 1e-5f);
        A1[co] = scale1 * inv1;  B1[co] = be1[co] - m1[co] * inv1;
        A2[co] = scale2 * inv2;  B2[co] = be2[co] - m2[co] * inv2;
    }
}

// ---------------- activation packing ----------------
__global__ __launch_bounds__(256) void k_pack(
    const float* __restrict__ x, const float* __restrict__ mb,
    u64* __restrict__ bitsA, u64* __restrict__ bitsI)
{
    int tid = threadIdx.x;
    int p = blockIdx.x * 256 + tid;          // pixel (b,hw)
    int q = blockIdx.y;                       // 64-channel quarter
    int b = p / HWSZ, hw = p % HWSZ;
    const float* xa = x + ((size_t)(b * 512 + q * 64)) * HWSZ + hw;
    const float* xi = x + ((size_t)(b * 512 + 256 + q * 64)) * HWSZ + hw;
    const float* mbq = mb + q * 64;
    u64 wa = 0, wi = 0;
#pragma unroll 8
    for (int j = 0; j < 64; j++) {
        float va = xa[(size_t)j * HWSZ];
        float vi = xi[(size_t)j * HWSZ] + mbq[j];
        wa |= (u64)(va >= 0.f) << j;
        wi |= (u64)(vi >= 0.f) << j;
    }
    bitsA[(size_t)p * 4 + q] = wa;
    bitsI[(size_t)p * 4 + q] = wi;
}

// ---------------- conv1: 256->256 binary conv + bn + residual + clip ----------------
// wave g owns co [q*64+g*16,+16); lane owns 4 adjacent pixels (56%4==0: same row)
__global__ __launch_bounds__(256, 3) void k_conv1(
    const float* __restrict__ x, const u64* __restrict__ bitsA,
    const u64* __restrict__ w1b, const float* __restrict__ A1, const float* __restrict__ B1,
    u64* __restrict__ bitsC, u16* __restrict__ c1v)
{
    __shared__ __align__(16) u64 sw[2304];   // 64 co * 9 taps * 4 words
    __shared__ float sA[64], sB[64];
    __shared__ u16 spart[4][256];
    int tid = threadIdx.x;
    int q = blockIdx.y;
    int cobase = q * 64;
    {
        const u64* src = w1b + (size_t)cobase * 36;
#pragma unroll
        for (int i = 0; i < 9; i++) sw[tid + i * 256] = src[tid + i * 256];
        if (tid < 64) { sA[tid] = A1[cobase + tid]; sB[tid] = B1[cobase + tid]; }
    }
    __syncthreads();

    int g = tid >> 6, lane = tid & 63;
    int pix0 = blockIdx.x * 256 + lane * 4;
    int b = pix0 / HWSZ, hw = pix0 % HWSZ;
    int h = hw / WD, w = hw % WD;     // w % 4 == 0

    int accA[8][4], accB[8][4];
#pragma unroll
    for (int co = 0; co < 8; co++)
#pragma unroll
        for (int p = 0; p < 4; p++) { accA[co][p] = 0; accB[co][p] = 0; }

#pragma unroll 1
    for (int dy = -1; dy <= 1; dy++) {
        ulonglong2 plo[6], phi[6];
        int m[6];
        LOADPOS(bitsA);
        TAPROW(sw, accA, 0);
        TAPROW(sw, accB, 8);
    }

    int rowsv = 3 - (h == 0) - (h == WD - 1);
    int nv[4];
#pragma unroll
    for (int p = 0; p < 4; p++) {
        int wp_ = w + p;
        nv[p] = rowsv * (3 - (wp_ == 0) - (wp_ == WD - 1));
    }

    unsigned sb[4] = {0, 0, 0, 0};
    bool wr = (q < 2);
#pragma unroll
    for (int half = 0; half < 2; half++) {
#pragma unroll
        for (int co = 0; co < 8; co++) {
            int col = (g << 4) + half * 8 + co;
            int coG = cobase + col;
            int bit = half * 8 + co;
            float A = sA[col], B = sB[col];
            float4 xr = *(const float4*)(x + (size_t)(b * 512 + coG) * HWSZ + hw);
            int a0 = half ? accB[co][0] : accA[co][0];
            int a1 = half ? accB[co][1] : accA[co][1];
            int a2 = half ? accB[co][2] : accA[co][2];
            int a3 = half ? accB[co][3] : accA[co][3];
            float v0 = (float)((nv[0] << 8) - 2 * a0) * A + B + xr.x;
            float v1 = (float)((nv[1] << 8) - 2 * a1) * A + B + xr.y;
            float v2 = (float)((nv[2] << 8) - 2 * a2) * A + B + xr.z;
            float v3 = (float)((nv[3] << 8) - 2 * a3) * A + B + xr.w;
            sb[0] |= (unsigned)(v0 >= 0.f) << bit;
            sb[1] |= (unsigned)(v1 >= 0.f) << bit;
            sb[2] |= (unsigned)(v2 >= 0.f) << bit;
            sb[3] |= (unsigned)(v3 >= 0.f) << bit;
            if (wr) {
                ushort4 st;
                st.x = f2bf(clampf(v0)); st.y = f2bf(clampf(v1));
                st.z = f2bf(clampf(v2)); st.w = f2bf(clampf(v3));
                *(ushort4*)(c1v + (size_t)coG * NPIX + pix0) = st;
            }
        }
    }
#pragma unroll
    for (int p = 0; p < 4; p++) spart[g][lane * 4 + p] = (u16)sb[p];
    __syncthreads();
    if (g == 0) {
#pragma unroll
        for (int p = 0; p < 4; p++) {
            int pi = lane * 4 + p;
            u64 word = (u64)spart[0][pi] | ((u64)spart[1][pi] << 16)
                     | ((u64)spart[2][pi] << 32) | ((u64)spart[3][pi] << 48);
            bitsC[(size_t)(pix0 + p) * 4 + q] = word;
        }
    }
}

// ---------------- conv2: 512->256 binary conv + bn + shuffled residual + clip ----------------
// two passes (bitsC x w2e, bitsI x w2o) share acc; all allocas <=128B (promotable)
__global__ __launch_bounds__(256, 3) void k_conv2(
    const float* __restrict__ x, const float* __restrict__ mb,
    const u64* __restrict__ bitsC, const u64* __restrict__ bitsI,
    const u64* __restrict__ w2e, const u64* __restrict__ w2o,
    const float* __restrict__ A2, const float* __restrict__ B2,
    const u16* __restrict__ c1v, float* __restrict__ out)
{
    __shared__ __align__(16) u64 se[2304], so[2304];
    __shared__ float sA[64], sB[64], sM[32];
    int tid = threadIdx.x;
    int q = blockIdx.y;
    int cobase = q * 64;
    {
        const u64* srcE = w2e + (size_t)cobase * 36;
        const u64* srcO = w2o + (size_t)cobase * 36;
#pragma unroll
        for (int i = 0; i < 9; i++) { se[tid + i * 256] = srcE[tid + i * 256]; so[tid + i * 256] = srcO[tid + i * 256]; }
        if (tid < 64) { sA[tid] = A2[cobase + tid]; sB[tid] = B2[cobase + tid]; }
        if (tid < 32) { sM[tid] = mb[q * 32 + tid]; }
    }
    __syncthreads();

    int g = tid >> 6, lane = tid & 63;
    int pix0 = blockIdx.x * 256 + lane * 4;
    int b = pix0 / HWSZ, hw = pix0 % HWSZ;
    int h = hw / WD, w = hw % WD;

    int accA[8][4], accB[8][4];
#pragma unroll
    for (int co = 0; co < 8; co++)
#pragma unroll
        for (int p = 0; p < 4; p++) { accA[co][p] = 0; accB[co][p] = 0; }

    // pass 0: conv1-sign bits x even weights
#pragma unroll 1
    for (int dy = -1; dy <= 1; dy++) {
        ulonglong2 plo[6], phi[6];
        int m[6];
        LOADPOS(bitsC);
        TAPROW(se, accA, 0);
        TAPROW(se, accB, 8);
    }
    // pass 1: idle bits x odd weights
#pragma unroll 1
    for (int dy = -1; dy <= 1; dy++) {
        ulonglong2 plo[6], phi[6];
        int m[6];
        LOADPOS(bitsI);
        TAPROW(so, accA, 0);
        TAPROW(so, accB, 8);
    }

    int rowsv = 3 - (h == 0) - (h == WD - 1);
    int nv[4];
#pragma unroll
    for (int p = 0; p < 4; p++) {
        int wp_ = w + p;
        nv[p] = rowsv * (3 - (wp_ == 0) - (wp_ == WD - 1));
    }

#pragma unroll
    for (int half = 0; half < 2; half++) {
#pragma unroll
        for (int co = 0; co < 8; co++) {
            int col = (g << 4) + half * 8 + co;
            int coG = cobase + col;
            int cg2 = coG >> 1;
            float A = sA[col], B = sB[col];
            int a0 = half ? accB[co][0] : accA[co][0];
            int a1 = half ? accB[co][1] : accA[co][1];
            int a2 = half ? accB[co][2] : accA[co][2];
            int a3 = half ? accB[co][3] : accA[co][3];
            float r0, r1, r2, r3;
            if ((co & 1) == 0) {   // coG even
                ushort4 cv = *(const ushort4*)(c1v + (size_t)cg2 * NPIX + pix0);
                r0 = bf2f(cv.x); r1 = bf2f(cv.y); r2 = bf2f(cv.z); r3 = bf2f(cv.w);
            } else {
                float4 xi = *(const float4*)(x + (size_t)(b * 512 + 256 + cg2) * HWSZ + hw);
                float mbv = sM[col >> 1];
                r0 = xi.x + mbv; r1 = xi.y + mbv; r2 = xi.z + mbv; r3 = xi.w + mbv;
            }
            float4 ov;
            ov.x = clampf((float)((nv[0] << 9) - 2 * a0) * A + B + r0);
            ov.y = clampf((float)((nv[1] << 9) - 2 * a1) * A + B + r1);
            ov.z = clampf((float)((nv[2] << 9) - 2 * a2) * A + B + r2);
            ov.w = clampf((float)((nv[3] << 9) - 2 * a3) * A + B + r3);
            *(float4*)(out + (size_t)(b * 256 + coG) * HWSZ + hw) = ov;
        }
    }
}

extern "C" void kernel_launch(void* const* d_in, const int* in_sizes, int n_in,
                              void* d_out, int out_size, void* d_ws, size_t ws_size,
                              hipStream_t stream)
{
    const float* x   = (const float*)d_in[0];
    const float* w1  = (const float*)d_in[1];
    const float* w2  = (const float*)d_in[2];
    const float* g1  = (const float*)d_in[3];
    const float* be1 = (const float*)d_in[4];
    const float* m1  = (const float*)d_in[5];
    const float* v1  = (const float*)d_in[6];
    const float* g2  = (const float*)d_in[7];
    const float* be2 = (const float*)d_in[8];
    const float* m2  = (const float*)d_in[9];
    const float* v2  = (const float*)d_in[10];
    const float* mb  = (const float*)d_in[11];

    char* ws = (char*)d_ws;
    u64* w1b = (u64*)ws; ws += 73728;
    u64* w2e = (u64*)ws; ws += 73728;
    u64* w2o = (u64*)ws; ws += 73728;
    float* A1 = (float*)ws; ws += 1024;
    float* B1 = (float*)ws; ws += 1024;
    float* A2 = (float*)ws; ws += 1024;
    float* B2 = (float*)ws; ws += 1024;
    u64* bitsA = (u64*)ws; ws += (size_t)NPIX * 4 * 8;
    u64* bitsI = (u64*)ws; ws += (size_t)NPIX * 4 * 8;
    u64* bitsC = (u64*)ws; ws += (size_t)NPIX * 4 * 8;
    u16* c1v = (u16*)ws; ws += (size_t)128 * NPIX * 2;

    hipLaunchKernelGGL(k_wprep, dim3(256), dim3(256), 0, stream,
                       w1, w2, g1, be1, m1, v1, g2, be2, m2, v2,
                       w1b, w2e, w2o, A1, B1, A2, B2);
    hipLaunchKernelGGL(k_pack, dim3(196, 4), dim3(256), 0, stream, x, mb, bitsA, bitsI);
    hipLaunchKernelGGL(k_conv1, dim3(196, 4), dim3(256), 0, stream,
                       x, bitsA, w1b, A1, B1, bitsC, c1v);
    hipLaunchKernelGGL(k_conv2, dim3(196, 4), dim3(256), 0, stream,
                       x, mb, bitsC, bitsI, w2e, w2o, A2, B2, c1v, (float*)d_out);
}